// Round 6
// baseline (989.298 us; speedup 1.0000x reference)
//
#include <hip/hip_runtime.h>
#include <stdint.h>
#include <stddef.h>

// ---------------------------------------------------------------------------
// BoundingBox loss processor:
//   filter (maxconf > 0.6) -> sort by class-0 score desc (stable, idx asc)
//   -> greedy NMS (IoU > 0.5 suppress) -> per-class top-20 over kept
//   -> smooth-L1 vs targets + focal CE on (class0 top-20 > 0.5) -> /M
// ---------------------------------------------------------------------------

#define NCAP 8192
#define WROW (NCAP / 64)   // 128 u64 words per mask row
#define NCHUNK (NCAP / 64) // 128 chunks of 64 rows
#define LDIAG_CH 112       // chunks of diag staged in LDS (56 KB; tail reads global)

typedef unsigned long long u64;

// ---------------- workspace layout (all offsets 16-byte aligned) -----------
constexpr size_t OFF_CNT   = 0;                               // 2 x u32: [0]=F, [1]=M
constexpr size_t OFF_KEYS  = 256;                             // u64[NCAP]; dead after
                                                              // k_gather -> diagG aliases it
constexpr size_t OFF_SX1   = OFF_KEYS + 8ull * NCAP;          // f32[NCAP]
constexpr size_t OFF_SY1   = OFF_SX1 + 4ull * NCAP;
constexpr size_t OFF_SX2   = OFF_SY1 + 4ull * NCAP;
constexpr size_t OFF_SY2   = OFF_SX2 + 4ull * NCAP;
constexpr size_t OFF_AREA  = OFF_SY2 + 4ull * NCAP;
constexpr size_t OFF_SORIG = OFF_AREA + 4ull * NCAP;          // u32[NCAP]
constexpr size_t OFF_KEEPS = OFF_SORIG + 4ull * NCAP;         // u32[NCAP]
constexpr size_t OFF_KORIG = OFF_KEEPS + 4ull * NCAP;         // u32[NCAP]
constexpr size_t OFF_TOPV  = OFF_KORIG + 4ull * NCAP;         // f32[1024]
constexpr size_t OFF_TOPI  = OFF_TOPV + 4096;                 // i32[1024]
constexpr size_t OFF_MASK  = OFF_TOPI + 4096;                 // u64[NCAP*WROW] = 8 MB
constexpr size_t WS_NEED_MASK = OFF_MASK + 8ull * NCAP * WROW;

// ---------------- kernels ---------------------------------------------------

__global__ void k_init(unsigned int* cnt) {
  if (threadIdx.x < 2) cnt[threadIdx.x] = 0u;
}

// Per row: valid = max over C confs > 0.6; sort key = desc(class0 score) | row.
__global__ void k_filter(const float* __restrict__ conf, int N, int C,
                         u64* __restrict__ keys,
                         unsigned int* __restrict__ cnt) {
  int row = blockIdx.x * blockDim.x + threadIdx.x;
  if (row >= NCAP) return;
  u64 key;
  if (row < N) {
    const float* cr = conf + (size_t)row * C;
    float mx = cr[0];
    for (int c = 1; c < C; ++c) mx = fmaxf(mx, cr[c]);
    unsigned int k32;
    if (mx > 0.6f) {
      union { float f; unsigned int u; } s; s.f = cr[0];
      unsigned int u = s.u;
      // monotone float->uint (ascending), then invert for descending sort
      u = (u & 0x80000000u) ? ~u : (u | 0x80000000u);
      k32 = ~u;
      if (k32 == 0xFFFFFFFFu) k32 = 0xFFFFFFFEu;  // keep 0xFFFFFFFF = invalid
      atomicAdd(&cnt[0], 1u);
    } else {
      k32 = 0xFFFFFFFFu;  // invalid rows sort last
    }
    key = ((u64)k32 << 32) | (unsigned int)row;
  } else {
    key = ((u64)0xFFFFFFFFu << 32);  // pad
  }
  keys[row] = key;
}

// One-block LDS bitonic sort, ascending u64 (desc score, asc row on ties).
__global__ __launch_bounds__(1024) void k_sort(u64* __restrict__ keys) {
  __shared__ u64 sk[NCAP];  // 64 KiB
  int tid = threadIdx.x;
  for (int t = tid; t < NCAP; t += 1024) sk[t] = keys[t];
  __syncthreads();
  for (unsigned int k = 2; k <= NCAP; k <<= 1) {
    for (unsigned int j = k >> 1; j > 0; j >>= 1) {
      for (int t = tid; t < NCAP; t += 1024) {
        unsigned int p = (unsigned int)t ^ j;
        if (p > (unsigned int)t) {
          bool up = ((t & k) == 0);
          u64 x = sk[t], y = sk[p];
          bool sw = up ? (x > y) : (x < y);
          if (sw) { sk[t] = y; sk[p] = x; }
        }
      }
      __syncthreads();
    }
  }
  for (int t = tid; t < NCAP; t += 1024) keys[t] = sk[t];
}

// Gather boxes into sorted order, precompute areas.
__global__ void k_gather(const float* __restrict__ loc,
                         const u64* __restrict__ keys,
                         float* __restrict__ sx1, float* __restrict__ sy1,
                         float* __restrict__ sx2, float* __restrict__ sy2,
                         float* __restrict__ sarea, unsigned int* __restrict__ sorig) {
  int p = blockIdx.x * blockDim.x + threadIdx.x;
  if (p >= NCAP) return;
  unsigned int row = (unsigned int)(keys[p] & 0xFFFFFFFFull);
  const float* b = loc + (size_t)row * 4;
  float x1 = b[0], y1 = b[1], x2 = b[2], y2 = b[3];
  sx1[p] = x1; sy1[p] = y1; sx2[p] = x2; sy2[p] = y2;
  sarea[p] = (x2 - x1) * (y2 - y1);   // numpy op order, no FMA hazard
  sorig[p] = row;
}

// Pairwise IoU>0.5 bitmask, torchvision style: 64x64 tiles, 1 wave per block.
// Lower-triangle blocks (by < bx) are never read by k_scan -> skipped.
// Diagonal blocks additionally write the compact diagG[] array (k_scan greedy).
__global__ __launch_bounds__(64) void k_mask(
    const float* __restrict__ sx1, const float* __restrict__ sy1,
    const float* __restrict__ sx2, const float* __restrict__ sy2,
    const float* __restrict__ sarea,
    u64* __restrict__ mask, u64* __restrict__ diagG) {
  if (blockIdx.y < blockIdx.x) return;   // only words >= own chunk are consumed
  __shared__ float jx1[64], jy1[64], jx2[64], jy2[64], ja[64];
  int t = threadIdx.x;
  int jbase = blockIdx.y * 64;
  jx1[t] = sx1[jbase + t]; jy1[t] = sy1[jbase + t];
  jx2[t] = sx2[jbase + t]; jy2[t] = sy2[jbase + t];
  ja[t]  = sarea[jbase + t];
  __syncthreads();
  int i = blockIdx.x * 64 + t;
  float xi1 = sx1[i], yi1 = sy1[i], xi2 = sx2[i], yi2 = sy2[i], ai = sarea[i];
  u64 bits = 0ULL;
#pragma unroll 8
  for (int jj = 0; jj < 64; ++jj) {
    float xx1 = fmaxf(xi1, jx1[jj]);
    float yy1 = fmaxf(yi1, jy1[jj]);
    float xx2 = fminf(xi2, jx2[jj]);
    float yy2 = fminf(yi2, jy2[jj]);
    float w = fmaxf(xx2 - xx1, 0.0f);
    float h = fmaxf(yy2 - yy1, 0.0f);
    float inter = w * h;
    float den = ai + ja[jj] - inter;   // (ai + aj) - inter, numpy order
    float iou = inter / den;           // IEEE div; 0/0 -> NaN -> compare false
    if (iou > 0.5f) bits |= (1ULL << jj);
  }
  mask[(size_t)i * WROW + blockIdx.y] = bits;
  if (blockIdx.x == blockIdx.y) diagG[i] = bits;
}

// ---------------------------------------------------------------------------
// Chunked greedy scan, ONE block of 1024 threads (16 waves).
// DESIGN RULE (learned rounds 2/4/5): no global-loaded value may cross a
// __syncthreads() — the compiler spills any such payload to scratch and the
// chunk loop serializes on scratch round-trips. Here every global load is
// consumed in the same phase it is issued:
//   phase A (wave 0): greedy over chunk h using diag words from LDS
//     (staged once at kernel start) + rem[h]; publish keep-list to LDS.
//   phase B (all):    re-load ONLY the kept rows' mask words (w > h) from
//     global — addresses known post-decision — OR into LDS rem[].
// 2 barriers/chunk; persistent state = rem[] (1 KB LDS) only.
// ---------------------------------------------------------------------------
__global__ __launch_bounds__(1024) void k_scan(
    const u64* __restrict__ mask,
    const u64* __restrict__ diagG,
    unsigned int* __restrict__ cnt,
    unsigned int* __restrict__ keeps) {
  __shared__ u64 ldsDiag[LDIAG_CH * 64];   // 56 KB
  __shared__ u64 rem[WROW];                // removed-set
  __shared__ unsigned int ldsList[64];     // kept rows of current chunk
  __shared__ int ldsNk;
  const int tid = threadIdx.x;
  const int F = (int)cnt[0];
  const int nch = (F + 63) >> 6;

  for (int i = tid; i < LDIAG_CH * 64; i += 1024) ldsDiag[i] = diagG[i];
  for (int w = tid; w < WROW; w += 1024) rem[w] = 0;
  __syncthreads();

  int K = 0;
  for (int h = 0; h < nch; ++h) {
    // ---- phase A: wave 0 greedy (no global traffic for h < LDIAG_CH) ----
    if (tid < 64) {
      u64 sup = rem[h];                    // broadcast read
      u64 D = (h < LDIAG_CH) ? ldsDiag[(h << 6) + tid] : diagG[(h << 6) + tid];
      unsigned int Dlo = (unsigned int)D, Dhi = (unsigned int)(D >> 32);
      int remrows = F - (h << 6);
      u64 valid = (remrows >= 64) ? ~0ull : ((1ull << remrows) - 1ull);
      u64 undec = valid & ~sup;            // uniform across wave 0
      int nk = 0;
      while (undec) {
        int rr = __builtin_ctzll(undec);   // uniform -> scalar lane index
        unsigned int dlo = __builtin_amdgcn_readlane(Dlo, rr);
        unsigned int dhi = __builtin_amdgcn_readlane(Dhi, rr);
        // clear rr itself too: degenerate boxes can give NaN self-IoU
        undec &= ~(((u64)dhi << 32) | (u64)dlo | (1ull << rr));
        if (tid == 0) {
          unsigned int ridx = (unsigned int)((h << 6) + rr);
          ldsList[nk] = ridx;
          keeps[K + nk] = ridx;
        }
        ++nk;
      }
      K += nk;
      if (tid == 0) ldsNk = nk;
    }
    __syncthreads();   // ldsList/ldsNk visible

    // ---- phase B: load kept rows' words (w > h), OR into rem ----
    const int nk = ldsNk;
    const int w = tid & 127;     // mask word this thread owns
    if (w > h && nk > 0) {
      const int sub = tid >> 7;  // 0..7 : which kept-rows this thread covers
      u64 acc = 0;
      for (int j = sub; j < nk; j += 32) {
        u64 v0 = mask[(size_t)ldsList[j] * WROW + w];
        u64 v1 = 0, v2 = 0, v3 = 0;
        if (j + 8  < nk) v1 = mask[(size_t)ldsList[j + 8]  * WROW + w];
        if (j + 16 < nk) v2 = mask[(size_t)ldsList[j + 16] * WROW + w];
        if (j + 24 < nk) v3 = mask[(size_t)ldsList[j + 24] * WROW + w];
        acc |= (v0 | v1) | (v2 | v3);
      }
      if (acc) atomicOr(&rem[w], acc);
    }
    __syncthreads();   // rem updates visible for next chunk's phase A
  }
  if (tid == 0) cnt[1] = (unsigned int)K;
}

// Fallback (small workspace): on-the-fly IoU greedy scan in one block.
__global__ __launch_bounds__(256) void k_scan_nomask(
    const float* __restrict__ sx1, const float* __restrict__ sy1,
    const float* __restrict__ sx2, const float* __restrict__ sy2,
    const float* __restrict__ sarea,
    unsigned int* __restrict__ cnt,
    unsigned int* __restrict__ keeps) {
  __shared__ unsigned char sup[NCAP];
  __shared__ int sK;
  int tid = threadIdx.x;
  int F = (int)cnt[0];
  for (int j = tid; j < NCAP; j += 256) sup[j] = 0;
  if (tid == 0) sK = 0;
  __syncthreads();
  for (int i = 0; i < F; ++i) {
    if (!sup[i]) {
      if (tid == 0) keeps[sK++] = (unsigned int)i;
      float xi1 = sx1[i], yi1 = sy1[i], xi2 = sx2[i], yi2 = sy2[i], ai = sarea[i];
      for (int j = i + 1 + tid; j < F; j += 256) {
        if (sup[j]) continue;
        float xx1 = fmaxf(xi1, sx1[j]);
        float yy1 = fmaxf(yi1, sy1[j]);
        float xx2 = fminf(xi2, sx2[j]);
        float yy2 = fminf(yi2, sy2[j]);
        float w = fmaxf(xx2 - xx1, 0.0f);
        float h = fmaxf(yy2 - yy1, 0.0f);
        float inter = w * h;
        float iou = inter / (ai + sarea[j] - inter);
        if (iou > 0.5f) sup[j] = 1;
      }
    }
    __syncthreads();
  }
  if (tid == 0) cnt[1] = (unsigned int)sK;
}

// kept (sorted-space) -> original row indices
__global__ void k_keptorig(const unsigned int* __restrict__ sorig,
                           const unsigned int* __restrict__ keeps,
                           unsigned int* __restrict__ korig,
                           const unsigned int* __restrict__ cnt) {
  int j = blockIdx.x * blockDim.x + threadIdx.x;
  if (j < (int)cnt[1]) korig[j] = sorig[keeps[j]];
}

// Per class (block), top-KT over the M kept boxes; lax.top_k tie semantics.
__global__ __launch_bounds__(256) void k_topk(
    const float* __restrict__ conf,
    const unsigned int* __restrict__ korig,
    const unsigned int* __restrict__ cnt,
    int C, int KT,
    float* __restrict__ topv, int* __restrict__ topi) {
  __shared__ float col[NCAP];
  __shared__ unsigned char flags[NCAP];
  __shared__ float rv[256];
  __shared__ int ri[256];
  int tid = threadIdx.x;
  int c = blockIdx.x;
  int M = (int)cnt[1];
  for (int j = tid; j < M; j += 256) {
    col[j] = conf[(size_t)korig[j] * C + c];
    flags[j] = 0;
  }
  __syncthreads();
  for (int t = 0; t < KT; ++t) {
    float bv = -3.402823466e+38f;
    int bj = 0x7FFFFFFF;
    for (int j = tid; j < M; j += 256) {
      if (flags[j]) continue;
      float v = col[j];
      if (v > bv || (v == bv && j < bj)) { bv = v; bj = j; }
    }
    rv[tid] = bv; ri[tid] = bj;
    __syncthreads();
    for (int ss = 128; ss > 0; ss >>= 1) {
      if (tid < ss) {
        float v2 = rv[tid + ss]; int j2 = ri[tid + ss];
        if (v2 > rv[tid] || (v2 == rv[tid] && j2 < ri[tid])) { rv[tid] = v2; ri[tid] = j2; }
      }
      __syncthreads();
    }
    if (tid == 0) {
      int w = ri[0];
      if (w == 0x7FFFFFFF) w = 0;    // M < KT safety; reference would crash here
      else flags[w] = 1;
      topv[c * KT + t] = rv[0];
      topi[c * KT + t] = w;
    }
    __syncthreads();
  }
}

// Final scalar: smooth-L1 over (KT, C, 4) gathered boxes + focal CE on
// (class0 top-KT > 0.5), divided by M.
__global__ __launch_bounds__(256) void k_loss(
    const float* __restrict__ loc, const float* __restrict__ tb,
    const int* __restrict__ labels,
    const unsigned int* __restrict__ korig,
    const float* __restrict__ topv, const int* __restrict__ topi,
    const unsigned int* __restrict__ cnt, int C, int KT,
    float* __restrict__ out) {
  __shared__ float red[256];
  int tid = threadIdx.x;
  int F = (int)cnt[0];
  int M = (int)cnt[1];
  if (F == 0 || M == 0) {
    if (tid == 0) out[0] = 0.001f;
    return;
  }
  int total = KT * C * 4;
  float part = 0.0f;
  for (int e = tid; e < total; e += 256) {
    int d = e & 3;
    int q = e >> 2;
    int c = q % C;
    int i = q / C;
    int j = topi[c * KT + i];
    unsigned int orow = korig[j];
    float pred = loc[(size_t)orow * 4 + d];
    float tg = tb[c * 4 + d];
    float dd = fabsf(pred - tg);
    part += (dd < 1.0f) ? (0.5f * dd * dd) : (dd - 0.5f);
  }
  red[tid] = part;
  __syncthreads();
  for (int s = 128; s > 0; s >>= 1) {
    if (tid < s) red[tid] += red[tid + s];
    __syncthreads();
  }
  if (tid == 0) {
    float loc_loss = red[0];
    float mx = -3.402823466e+38f;
    for (int i = 0; i < KT; ++i) {
      float x = (topv[i] > 0.5f) ? 1.0f : 0.0f;   // class 0 column
      mx = fmaxf(mx, x);
    }
    float ssum = 0.0f;
    for (int i = 0; i < KT; ++i) {
      float x = (topv[i] > 0.5f) ? 1.0f : 0.0f;
      ssum += expf(x - mx);
    }
    float lse = mx + logf(ssum);
    float ce = 0.0f;
    for (int i = 0; i < KT; ++i) {
      float x = (topv[i] > 0.5f) ? 1.0f : 0.0f;
      ce += (float)labels[i] * (x - lse);
    }
    ce = -ce;
    float pt = expf(-ce);
    float om = 1.0f - pt;
    float conf_loss = 0.25f * om * om * ce;   // ALPHA=0.25, GAMMA=2
    out[0] = (loc_loss + conf_loss) / (float)M;
  }
}

// ---------------- host ------------------------------------------------------

extern "C" void kernel_launch(void* const* d_in, const int* in_sizes, int n_in,
                              void* d_out, int out_size, void* d_ws, size_t ws_size,
                              hipStream_t stream) {
  (void)n_in; (void)out_size;
  const float* loc    = (const float*)d_in[0];
  const float* conf   = (const float*)d_in[1];
  const float* tb     = (const float*)d_in[2];
  const int*   labels = (const int*)d_in[3];
  float* out = (float*)d_out;

  int N = in_sizes[0] / 4;
  if (N > NCAP) N = NCAP;
  int C  = (N > 0) ? (in_sizes[1] / N) : 20;
  int KT = in_sizes[3];

  char* ws = (char*)d_ws;
  unsigned int* cnt   = (unsigned int*)(ws + OFF_CNT);
  u64*          keys  = (u64*)(ws + OFF_KEYS);
  float*        sx1   = (float*)(ws + OFF_SX1);
  float*        sy1   = (float*)(ws + OFF_SY1);
  float*        sx2   = (float*)(ws + OFF_SX2);
  float*        sy2   = (float*)(ws + OFF_SY2);
  float*        sarea = (float*)(ws + OFF_AREA);
  unsigned int* sorig = (unsigned int*)(ws + OFF_SORIG);
  unsigned int* keeps = (unsigned int*)(ws + OFF_KEEPS);
  unsigned int* korig = (unsigned int*)(ws + OFF_KORIG);
  float*        topv  = (float*)(ws + OFF_TOPV);
  int*          topi  = (int*)(ws + OFF_TOPI);
  u64*          diagG = (u64*)(ws + OFF_KEYS);   // aliases keys (dead after k_gather)
  u64*          mask  = (u64*)(ws + OFF_MASK);

  bool use_mask = (ws_size >= WS_NEED_MASK);

  k_init<<<1, 64, 0, stream>>>(cnt);
  k_filter<<<NCAP / 256, 256, 0, stream>>>(conf, N, C, keys, cnt);
  k_sort<<<1, 1024, 0, stream>>>(keys);
  k_gather<<<NCAP / 256, 256, 0, stream>>>(loc, keys, sx1, sy1, sx2, sy2, sarea, sorig);
  if (use_mask) {
    k_mask<<<dim3(WROW, WROW), 64, 0, stream>>>(sx1, sy1, sx2, sy2, sarea, mask, diagG);
    k_scan<<<1, 1024, 0, stream>>>(mask, diagG, cnt, keeps);
  } else {
    k_scan_nomask<<<1, 256, 0, stream>>>(sx1, sy1, sx2, sy2, sarea, cnt, keeps);
  }
  k_keptorig<<<NCAP / 256, 256, 0, stream>>>(sorig, keeps, korig, cnt);
  k_topk<<<C, 256, 0, stream>>>(conf, korig, cnt, C, KT, topv, topi);
  k_loss<<<1, 256, 0, stream>>>(loc, tb, labels, korig, topv, topi, cnt, C, KT, out);
}